// Round 8
// baseline (322.077 us; speedup 1.0000x reference)
//
#include <hip/hip_runtime.h>
#include <hip/hip_bf16.h>
#include <hip/hip_cooperative_groups.h>
#include <math.h>

namespace cg = cooperative_groups;

#define NN 2048      // nodes
#define NE 4096      // edges
#define D 128
#define NODE_K 1024
#define EDGE_K 2048
#define CAP 64       // per-node incident-edge list capacity (mean degree 4)
#define ROWS 16      // rows per block in GEMM phases
#define BT 512       // threads per block (8 waves)
#define GRID 256     // cooperative grid: 1 block/CU

typedef const __hip_bfloat16* bfp;
__device__ __forceinline__ float b2f(__hip_bfloat16 x) { return __bfloat162float(x); }

// dual-path loads: f=1 -> fp32 input, f=0 -> bf16 input (bf16->fp32 is exact)
__device__ __forceinline__ float ldx(const void* p, size_t i, int f) {
  return f ? ((const float*)p)[i] : b2f(((bfp)p)[i]);
}
__device__ __forceinline__ float4 ldx4(const void* p, size_t i4, int f) {
  if (f) return ((const float4*)p)[i4];
  ushort4 u = ((const ushort4*)p)[i4];
  float4 r;
  r.x = b2f(*(const __hip_bfloat16*)&u.x);
  r.y = b2f(*(const __hip_bfloat16*)&u.y);
  r.z = b2f(*(const __hip_bfloat16*)&u.z);
  r.w = b2f(*(const __hip_bfloat16*)&u.w);
  return r;
}

struct MegaArgs {
  const void *nf, *ef;
  const int *src, *dst;
  const void *wrn, *wre, *we, *wn, *wq, *wk, *wv, *wo, *w1, *b1, *w2, *b2;
  float *ns, *es;
  int *node_mask, *edge_topk, *deg, *lists;
  float *qkv, *ao;
  void *out;
};

// shared GEMM pass: acc[4] += As(16x128 LDS) @ Wg(128x128 global, dual-path)
// thread t: j = t&127 (output col), rg = t>>7 in 0..3 (4 rows each)
__device__ __forceinline__ void gemm_pass(const void* __restrict__ Wg, int f,
                                          float* __restrict__ Wl,
                                          const float* __restrict__ As,
                                          int j, int rg, float acc[4]) {
  for (int half = 0; half < 2; ++half) {
    __syncthreads();
    for (int i = threadIdx.x; i < 64 * D / 4; i += BT)
      ((float4*)Wl)[i] = ldx4(Wg, half * (64 * D / 4) + i, f);
    __syncthreads();
    #pragma unroll 4
    for (int k4 = 0; k4 < 16; ++k4) {
      int kr = k4 * 4;
      int k0 = half * 64 + kr;
      float w0 = Wl[(kr + 0) * D + j];
      float w1 = Wl[(kr + 1) * D + j];
      float w2 = Wl[(kr + 2) * D + j];
      float w3 = Wl[(kr + 3) * D + j];
      #pragma unroll
      for (int r = 0; r < 4; ++r) {
        float4 a = ((const float4*)As)[((rg * 4 + r) * D + k0) >> 2];
        acc[r] += a.x * w0 + a.y * w1 + a.z * w2 + a.w * w3;
      }
    }
  }
}

__global__ __launch_bounds__(BT) void mega_kernel(MegaArgs a) {
  cg::grid_group grid = cg::this_grid();
  __shared__ __align__(16) float smem[12288];  // 48 KB, carved per phase
  __shared__ int s8[8];
  int b = blockIdx.x, t = threadIdx.x;
  int wave = t >> 6, lane = t & 63;

  // ---- P0: per-block dtype detect (first 4096 halves of node_features) ----
  int f;
  {
    const unsigned short* raw = (const unsigned short*)a.nf;
    int weird = 0;
    for (int i = t; i < 4096; i += BT) {
      unsigned int bits = ((unsigned int)raw[i]) << 16;
      float x = __uint_as_float(bits);
      float ax = fabsf(x);
      if (!(ax <= 1e3f) || (x != 0.f && ax < 1e-12f)) weird++;  // nan/inf/huge/denorm
    }
    #pragma unroll
    for (int m = 32; m >= 1; m >>= 1) weird += __shfl_xor(weird, m);
    if (lane == 0) s8[wave] = weird;
    __syncthreads();
    int tot = 0;
    #pragma unroll
    for (int i = 0; i < 8; ++i) tot += s8[i];
    f = (tot > 200) ? 1 : 0;  // 1 => inputs are fp32
  }

  // ---- P1: zero deg + router scores (fp64 acc for rank stability) ----
  if (b < 8 && t < 256) a.deg[b * 256 + t] = 0;
  for (int rr = 0; rr < 3; ++rr) {
    int wid = rr * 2048 + b * 8 + wave;  // 0..6143
    const void* base; const void* w; float* out; size_t r0;
    if (wid < NN) { base = a.nf; r0 = (size_t)wid * D; w = a.wrn; out = a.ns + wid; }
    else { int r = wid - NN; base = a.ef; r0 = (size_t)r * D; w = a.wre; out = a.es + r; }
    double p = (double)ldx(base, r0 + lane, f) * (double)ldx(w, lane, f)
             + (double)ldx(base, r0 + lane + 64, f) * (double)ldx(w, lane + 64, f);
    #pragma unroll
    for (int m = 32; m >= 1; m >>= 1) p += __shfl_xor(p, m);
    if (lane == 0) *out = (float)p;
  }
  grid.sync();

  // ---- P2: exact top-k ranks (stable ties == lax.top_k) + incident lists ----
  for (int i = t; i < NN; i += BT) smem[i] = a.ns[i];
  for (int i = t; i < NE; i += BT) smem[NN + i] = a.es[i];
  __syncthreads();
  {
    int i = b * 8 + wave;  // node elem, 0..2047
    float si = smem[i];
    int rank = 0;
    for (int j = lane; j < NN; j += 64) {
      float sj = smem[j];
      rank += (sj > si) || (sj == si && j < i);
    }
    #pragma unroll
    for (int m = 32; m >= 1; m >>= 1) rank += __shfl_xor(rank, m);
    if (lane == 0) a.node_mask[i] = (rank < NODE_K) ? 1 : 0;
  }
  for (int rr = 0; rr < 2; ++rr) {
    int i = b * 16 + rr * 8 + wave;  // edge elem, 0..4095
    float si = smem[NN + i];
    int rank = 0;
    for (int j = lane; j < NE; j += 64) {
      float sj = smem[NN + j];
      rank += (sj > si) || (sj == si && j < i);
    }
    #pragma unroll
    for (int m = 32; m >= 1; m >>= 1) rank += __shfl_xor(rank, m);
    if (lane == 0) a.edge_topk[i] = (rank < EDGE_K) ? 1 : 0;
  }
  if (t < 16) {  // incident-edge lists (deg zeroed in P1, sync'd)
    int e = b * 16 + t;
    int sn = a.src[e], dn = a.dst[e];
    int p = atomicAdd(&a.deg[sn], 1);
    if (p >= 0 && p < CAP) a.lists[sn * CAP + p] = e;
    if (dn != sn) {
      p = atomicAdd(&a.deg[dn], 1);
      if (p >= 0 && p < CAP) a.lists[dn * CAP + p] = e;
    }
  }
  grid.sync();

  // ---- P3: gather -> h -> q,k,v (5 GEMM passes, rows [b*16, b*16+16)) ----
  {
    float* Wl = smem;                 // 8192 floats
    float* A1 = smem + 8192;          // 2048: efm, reused as h
    float* A2 = smem + 10240;         // 2048: nsum
    int row0 = b * ROWS;
    {
      int i = t;                      // exactly ROWS*D/4 = 512 float4 slots
      int e = row0 + (i >> 5), c4 = i & 31;
      int sn = a.src[e], dn = a.dst[e];
      float m = (a.edge_topk[e] && a.node_mask[sn] && a.node_mask[dn]) ? 1.f : 0.f;
      float4 ef4 = ldx4(a.ef, (size_t)e * 32 + c4, f);
      ((float4*)A1)[i] = make_float4(m * ef4.x, m * ef4.y, m * ef4.z, m * ef4.w);
      float4 s4 = ldx4(a.nf, (size_t)sn * 32 + c4, f);
      float4 d4 = ldx4(a.nf, (size_t)dn * 32 + c4, f);
      ((float4*)A2)[i] = make_float4(s4.x + d4.x, s4.y + d4.y, s4.z + d4.z, s4.w + d4.w);
    }
    int j = t & 127, rg = t >> 7;
    float acc[4] = {0, 0, 0, 0};
    gemm_pass(a.we, f, Wl, A1, j, rg, acc);   // h += efm @ w_e (leading sync covers A1)
    gemm_pass(a.wn, f, Wl, A2, j, rg, acc);   // h += nsum @ w_n
    __syncthreads();
    #pragma unroll
    for (int r = 0; r < 4; ++r) A1[(rg * 4 + r) * D + j] = acc[r];  // A1 := h
    for (int sel = 0; sel < 3; ++sel) {
      const void* Ws = (sel == 0) ? a.wq : (sel == 1) ? a.wk : a.wv;
      float a2[4] = {0, 0, 0, 0};
      gemm_pass(Ws, f, Wl, A1, j, rg, a2);    // leading sync makes h visible
      float* C = a.qkv + (size_t)sel * NE * D;
      #pragma unroll
      for (int r = 0; r < 4; ++r) C[(size_t)(row0 + rg * 4 + r) * D + j] = a2[r];
    }
  }
  grid.sync();

  // ---- P4: sparse edge attention (4 edges per block per iter, 4 iters) ----
  {
    const float* q = a.qkv;
    const float* k = a.qkv + NE * D;
    const float* v = a.qkv + 2 * NE * D;
    const float scale = 0.17677669529663687f;  // 1/sqrt(32)
    int j = t & 127;
    for (int it = 0; it < 4; ++it) {
      int e = it * 1024 + b * 4 + (t >> 7);
      float qj = q[e * D + j];
      int sn = a.src[e], dn = a.dst[e];
      float m = -1e30f, l = 0.f, acc = 0.f;
      int degA = max(0, min(a.deg[sn], CAP));
      for (int i = 0; i < degA; ++i) {
        int fe = a.lists[sn * CAP + i];
        float p = qj * k[fe * D + j];
        p += __shfl_xor(p, 16); p += __shfl_xor(p, 8); p += __shfl_xor(p, 4);
        p += __shfl_xor(p, 2);  p += __shfl_xor(p, 1);
        float s = p * scale;
        float vj = v[fe * D + j];
        float mn = fmaxf(m, s);
        float corr = expf(m - mn);
        float w = expf(s - mn);
        l = l * corr + w;
        acc = acc * corr + w * vj;
        m = mn;
      }
      if (dn != sn) {
        int degB = max(0, min(a.deg[dn], CAP));
        for (int i = 0; i < degB; ++i) {
          int fe = a.lists[dn * CAP + i];
          if (a.src[fe] == sn || a.dst[fe] == sn) continue;  // already in list A
          float p = qj * k[fe * D + j];
          p += __shfl_xor(p, 16); p += __shfl_xor(p, 8); p += __shfl_xor(p, 4);
          p += __shfl_xor(p, 2);  p += __shfl_xor(p, 1);
          float s = p * scale;
          float vj = v[fe * D + j];
          float mn = fmaxf(m, s);
          float corr = expf(m - mn);
          float w = expf(s - mn);
          l = l * corr + w;
          acc = acc * corr + w * vj;
          m = mn;
        }
      }
      a.ao[e * D + j] = acc / fmaxf(l, 1e-37f);
    }
  }
  grid.sync();

  // ---- P5: o = ao@WO; x = gelu(o@W1+b1); logits = x@W2+b2 ----
  {
    float* Wl = smem;                 // 8192 floats
    float* Al = smem + 8192;          // ao rows, reused as x
    float* Bl = smem + 10240;         // o rows
    int row0 = b * ROWS;
    ((float4*)Al)[t] = ((const float4*)a.ao)[(size_t)b * (ROWS * D / 4) + t];
    int j = t & 127, rg = t >> 7;
    float acc[4] = {0, 0, 0, 0};
    gemm_pass(a.wo, f, Wl, Al, j, rg, acc);   // o = ao @ w_o
    __syncthreads();
    #pragma unroll
    for (int r = 0; r < 4; ++r) Bl[(rg * 4 + r) * D + j] = acc[r];
    float acc2[4] = {0, 0, 0, 0};
    gemm_pass(a.w1, f, Wl, Bl, j, rg, acc2);  // leading sync makes Bl visible
    float bj = ldx(a.b1, j, f);
    __syncthreads();                          // all reads of Al done before overwrite
    #pragma unroll
    for (int r = 0; r < 4; ++r) {             // x = gelu(o@w1 + b1)
      float u = acc2[r] + bj;
      float inner = 0.7978845608028654f * (u + 0.044715f * u * u * u);
      Al[(rg * 4 + r) * D + j] = 0.5f * u * (1.f + tanhf(inner));
    }
    __syncthreads();
    for (int i = t; i < D * 16; i += BT) Wl[i] = ldx(a.w2, i, f);
    __syncthreads();
    if (t < 256) {                            // logits = x @ w2 + b2
      int r = t >> 4, c = t & 15;
      float s = 0.f;
      for (int kk = 0; kk < D; ++kk) s += Al[r * D + kk] * Wl[kk * 16 + c];
      s += ldx(a.b2, c, f);
      int idx = (row0 + r) * 16 + c;
      if (f) ((float*)a.out)[idx] = s;
      else ((__hip_bfloat16*)a.out)[idx] = __float2bfloat16(s);
    }
  }
}

extern "C" void kernel_launch(void* const* d_in, const int* in_sizes, int n_in,
                              void* d_out, int out_size, void* d_ws, size_t ws_size,
                              hipStream_t stream) {
  const int* eidx = (const int*)d_in[2];

  size_t off = 0;
  char* base = (char*)d_ws;
  auto alloc = [&](size_t nbytes) -> void* {
    void* p = base + off;
    off += (nbytes + 255) & ~(size_t)255;
    return p;
  };
  float* ns        = (float*)alloc(NN * sizeof(float));
  float* es        = (float*)alloc(NE * sizeof(float));
  int* node_mask   = (int*)alloc(NN * sizeof(int));
  int* edge_topk   = (int*)alloc(NE * sizeof(int));
  int* deg         = (int*)alloc(NN * sizeof(int));
  int* lists       = (int*)alloc((size_t)NN * CAP * sizeof(int));
  float* qkv       = (float*)alloc((size_t)3 * NE * D * sizeof(float));
  float* ao        = (float*)alloc((size_t)NE * D * sizeof(float));

  MegaArgs ka;
  ka.nf = d_in[0];  ka.ef = d_in[1];
  ka.src = eidx;    ka.dst = eidx + NE;
  ka.wrn = d_in[3]; ka.wre = d_in[4];
  ka.we = d_in[5];  ka.wn = d_in[6];
  ka.wq = d_in[7];  ka.wk = d_in[8]; ka.wv = d_in[9];
  ka.wo = d_in[10]; ka.w1 = d_in[11]; ka.b1 = d_in[12];
  ka.w2 = d_in[13]; ka.b2 = d_in[14];
  ka.ns = ns; ka.es = es;
  ka.node_mask = node_mask; ka.edge_topk = edge_topk;
  ka.deg = deg; ka.lists = lists;
  ka.qkv = qkv; ka.ao = ao;
  ka.out = d_out;

  void* params[] = { (void*)&ka };
  hipLaunchCooperativeKernel((const void*)mega_kernel, dim3(GRID), dim3(BT),
                             params, 0, stream);
}

// Round 9
// 146.450 us; speedup vs baseline: 2.1992x; 2.1992x over previous
//
#include <hip/hip_runtime.h>
#include <hip/hip_bf16.h>
#include <math.h>

#define NN 2048      // nodes
#define NE 4096      // edges
#define D 128
#define NODE_K 1024
#define EDGE_K 2048
#define CAP 64       // per-node incident-edge list capacity (mean degree 4)

typedef const __hip_bfloat16* bfp;
typedef __attribute__((ext_vector_type(8))) short short8;     // 8 bf16 (4 VGPRs)
typedef __attribute__((ext_vector_type(4))) float floatx4;    // MFMA acc

#define MFMA16(a, b, c) __builtin_amdgcn_mfma_f32_16x16x32_bf16(a, b, c, 0, 0, 0)

__device__ __forceinline__ float b2f(__hip_bfloat16 x) { return __bfloat162float(x); }

// dual-path loads: f=1 -> fp32 input, f=0 -> bf16 input (bf16->fp32 is exact)
__device__ __forceinline__ float ldx(const void* p, size_t i, int f) {
  return f ? ((const float*)p)[i] : b2f(((bfp)p)[i]);
}
__device__ __forceinline__ float4 ldx4(const void* p, size_t i4, int f) {
  if (f) return ((const float4*)p)[i4];
  ushort4 u = ((const ushort4*)p)[i4];
  float4 r;
  r.x = __uint_as_float(((unsigned)u.x) << 16);
  r.y = __uint_as_float(((unsigned)u.y) << 16);
  r.z = __uint_as_float(((unsigned)u.z) << 16);
  r.w = __uint_as_float(((unsigned)u.w) << 16);
  return r;
}

// RNE fp32 -> (bf16 hi, bf16 lo): x ~= hi + lo, dropped part ~2^-17 |x|
__device__ __forceinline__ void split2(float x, unsigned short& hi, unsigned short& lo) {
  unsigned u = __float_as_uint(x);
  unsigned h = (u + 0x7FFFu + ((u >> 16) & 1u)) >> 16;
  hi = (unsigned short)h;
  float r = x - __uint_as_float(h << 16);
  unsigned v = __float_as_uint(r);
  lo = (unsigned short)((v + 0x7FFFu + ((v >> 16) & 1u)) >> 16);
}
__device__ __forceinline__ void build_frags(const float* v8, short8& fh, short8& fl) {
  #pragma unroll
  for (int i = 0; i < 8; ++i) {
    unsigned short h, l;
    split2(v8[i], h, l);
    fh[i] = (short)h; fl[i] = (short)l;
  }
}

// per-block dtype detect from first 4096 halves of node_features (8 KB, L2-hot)
__device__ __forceinline__ int detect_f(const unsigned short* raw, int* s4) {
  int t = threadIdx.x;
  int weird = 0;
  for (int i = t; i < 4096; i += blockDim.x) {
    unsigned int bits = ((unsigned int)raw[i]) << 16;
    float x = __uint_as_float(bits);
    float ax = fabsf(x);
    if (!(ax <= 1e3f) || (x != 0.f && ax < 1e-12f)) weird++;  // nan/inf/huge/denorm
  }
  #pragma unroll
  for (int m = 32; m >= 1; m >>= 1) weird += __shfl_xor(weird, m);
  int nw = (int)blockDim.x >> 6;
  if ((t & 63) == 0) s4[t >> 6] = weird;
  __syncthreads();
  int tot = 0;
  for (int i = 0; i < nw; ++i) tot += s4[i];
  return (tot > 200) ? 1 : 0;  // 1 => inputs are fp32
}

struct K1Args {
  const void *nf, *ef, *wrn, *wre;
  const void* w[7];              // we, wn, wq, wk, wv, wo, w1 (each 128x128)
  float *ns, *es;
  int *deg, *flag;
  unsigned short *wtHi, *wtLo;   // [7][128 n][128 k] bf16 bits (transposed+split)
};

// ---------- K1: router scores (fp64) + deg zero + flag + weight split/transpose ----
#define SCORE_BLOCKS ((NN + NE) / 4)
#define WPREP_BLOCKS 56          // 7*16384 / 2048
__global__ __launch_bounds__(256) void scores_prep_kernel(K1Args a) {
  __shared__ int s4[4];
  int b = blockIdx.x, t = threadIdx.x;
  int f = detect_f((const unsigned short*)a.nf, s4);
  if (b < SCORE_BLOCKS) {
    int wid = b * 4 + (t >> 6), lane = t & 63;
    const void* base; const void* w; float* out; size_t r0;
    if (wid < NN) { base = a.nf; r0 = (size_t)wid * D; w = a.wrn; out = a.ns + wid; }
    else { int r = wid - NN; base = a.ef; r0 = (size_t)r * D; w = a.wre; out = a.es + r; }
    double p = (double)ldx(base, r0 + lane, f) * (double)ldx(w, lane, f)
             + (double)ldx(base, r0 + lane + 64, f) * (double)ldx(w, lane + 64, f);
    #pragma unroll
    for (int m = 32; m >= 1; m >>= 1) p += __shfl_xor(p, m);
    if (lane == 0) *out = (float)p;
  } else if (b == SCORE_BLOCKS) {
    if (t == 0) a.flag[0] = f;
    for (int i = t; i < NN; i += 256) a.deg[i] = 0;
  } else {  // weight split + transpose: Wt[n][k] = split(W[k][n])
    int wb = b - SCORE_BLOCKS - 1;  // 0..55
    #pragma unroll
    for (int i = 0; i < 8; ++i) {
      int g = wb * 2048 + i * 256 + t;   // 0..114687
      int w = g >> 14, r = g & 16383;
      int k = r >> 7, n = r & 127;
      float x = ldx(a.w[w], r, f);
      unsigned short hi, lo;
      split2(x, hi, lo);
      a.wtHi[w * 16384 + n * 128 + k] = hi;
      a.wtLo[w * 16384 + n * 128 + k] = lo;
    }
  }
}

// ---------- K2: node rank + edge rank + incident lists ----------
#define NMB (NN / 4)
#define EMB (NE / 4)
__global__ __launch_bounds__(256) void mask_lists_kernel(
    const float* __restrict__ ns, const float* __restrict__ es,
    const int* __restrict__ src, const int* __restrict__ dst,
    int* __restrict__ node_mask, int* __restrict__ edge_topk,
    int* __restrict__ deg, int* __restrict__ lists) {
  __shared__ float s[NE];
  int b = blockIdx.x, t = threadIdx.x;
  if (b < NMB) {  // exact top-k rank, stable ties (== lax.top_k)
    for (int i = t; i < NN; i += 256) s[i] = ns[i];
    __syncthreads();
    int i = b * 4 + (t >> 6), lane = t & 63;
    float si = s[i];
    int rank = 0;
    for (int j = lane; j < NN; j += 64) {
      float sj = s[j];
      rank += (sj > si) || (sj == si && j < i);
    }
    #pragma unroll
    for (int m = 32; m >= 1; m >>= 1) rank += __shfl_xor(rank, m);
    if (lane == 0) node_mask[i] = (rank < NODE_K) ? 1 : 0;
  } else if (b < NMB + EMB) {
    for (int i = t; i < NE; i += 256) s[i] = es[i];
    __syncthreads();
    int i = (b - NMB) * 4 + (t >> 6), lane = t & 63;
    float si = s[i];
    int rank = 0;
    for (int j = lane; j < NE; j += 64) {
      float sj = s[j];
      rank += (sj > si) || (sj == si && j < i);
    }
    #pragma unroll
    for (int m = 32; m >= 1; m >>= 1) rank += __shfl_xor(rank, m);
    if (lane == 0) edge_topk[i] = (rank < EDGE_K) ? 1 : 0;
  } else {
    int e = (b - NMB - EMB) * 256 + t;
    if (e < NE) {
      int sn = src[e], dn = dst[e];
      int p = atomicAdd(&deg[sn], 1);
      if (p >= 0 && p < CAP) lists[sn * CAP + p] = e;
      if (dn != sn) {
        p = atomicAdd(&deg[dn], 1);
        if (p >= 0 && p < CAP) lists[dn * CAP + p] = e;
      }
    }
  }
}

// ---------- K3: MFMA h = efm@WE + nsum@WN; q,k,v = h@WQ/WK/WV ----------
// block: 512 thr (8 waves), 16 edge rows; wave w owns col-tile n0 = w*16.
// split-x3: D += Ahi*Bhi + Alo*Bhi + Ahi*Blo  (~1e-5 relative; fp32 acc)
__global__ __launch_bounds__(512) void h_qkv_mfma_kernel(
    const void* __restrict__ ef, const void* __restrict__ nf,
    const int* __restrict__ src, const int* __restrict__ dst,
    const int* __restrict__ node_mask, const int* __restrict__ edge_topk,
    const int* __restrict__ flag,
    const unsigned short* __restrict__ wtHi, const unsigned short* __restrict__ wtLo,
    float* __restrict__ qkv) {
  __shared__ __align__(16) float hf[8 * 64 * 4];  // frag-order h (fp32), 8 KB
  int t = threadIdx.x;
  int wave = t >> 6, lane = t & 63;
  int q = lane >> 4, c = lane & 15;
  int f = flag[0];
  int row0 = blockIdx.x * 16;
  int e = row0 + c;                 // A-row this lane gathers (m = c)
  int sn = src[e], dn = dst[e];
  float em = (edge_topk[e] && node_mask[sn] && node_mask[dn]) ? 1.f : 0.f;
  int n0 = wave * 16;               // col-tile
  const unsigned short* WEh = wtHi;             const unsigned short* WEl = wtLo;
  const unsigned short* WNh = wtHi + 16384;     const unsigned short* WNl = wtLo + 16384;

  floatx4 acc = {0.f, 0.f, 0.f, 0.f};
  #pragma unroll
  for (int ks = 0; ks < 4; ++ks) {
    int k0 = ks * 32 + q * 8;
    size_t i4 = ((size_t)e * D + k0) >> 2;
    float4 e0 = ldx4(ef, i4, f), e1 = ldx4(ef, i4 + 1, f);
    size_t s4i = ((size_t)sn * D + k0) >> 2;
    size_t d4i = ((size_t)dn * D + k0) >> 2;
    float4 s0 = ldx4(nf, s4i, f), s1 = ldx4(nf, s4i + 1, f);
    float4 d0 = ldx4(nf, d4i, f), d1 = ldx4(nf, d4i + 1, f);
    float a1[8] = {em * e0.x, em * e0.y, em * e0.z, em * e0.w,
                   em * e1.x, em * e1.y, em * e1.z, em * e1.w};
    float a2[8] = {s0.x + d0.x, s0.y + d0.y, s0.z + d0.z, s0.w + d0.w,
                   s1.x + d1.x, s1.y + d1.y, s1.z + d1.z, s1.w + d1.w};
    short8 a1h, a1l, a2h, a2l;
    build_frags(a1, a1h, a1l);
    build_frags(a2, a2h, a2l);
    size_t bo = (size_t)(n0 + c) * 128 + k0;
    short8 bEh = *(const short8*)(WEh + bo);
    short8 bEl = *(const short8*)(WEl + bo);
    short8 bNh = *(const short8*)(WNh + bo);
    short8 bNl = *(const short8*)(WNl + bo);
    acc = MFMA16(a1h, bEh, acc);
    acc = MFMA16(a1l, bEh, acc);
    acc = MFMA16(a1h, bEl, acc);
    acc = MFMA16(a2h, bNh, acc);
    acc = MFMA16(a2l, bNh, acc);
    acc = MFMA16(a2h, bNl, acc);
  }
  // write h (C-layout: row=4q+r, col=n0+c) into frag-order LDS
  {
    int np = n0 + c;
    int kd = np >> 5, qd = (np >> 3) & 3, half = (c >> 2) & 1, j4 = c & 3;
    #pragma unroll
    for (int r = 0; r < 4; ++r) {
      int destlane = qd * 16 + 4 * q + r;
      hf[((kd * 2 + half) * 64 + destlane) * 4 + j4] = acc[r];
    }
  }
  __syncthreads();
  // q, k, v passes: A = h from frag-order LDS (conflict-free lane*16B reads)
  #pragma unroll
  for (int sel = 0; sel < 3; ++sel) {
    const unsigned short* Bh = wtHi + (size_t)(2 + sel) * 16384;
    const unsigned short* Bl = wtLo + (size_t)(2 + sel) * 16384;
    floatx4 a2c = {0.f, 0.f, 0.f, 0.f};
    #pragma unroll
    for (int ks = 0; ks < 4; ++ks) {
      float4 p0 = *(const float4*)&hf[((ks * 2 + 0) * 64 + lane) * 4];
      float4 p1 = *(const float4*)&hf[((ks * 2 + 1) * 64 + lane) * 4];
      float v8[8] = {p0.x, p0.y, p0.z, p0.w, p1.x, p1.y, p1.z, p1.w};
      short8 ah, al;
      build_frags(v8, ah, al);
      size_t bo = (size_t)(n0 + c) * 128 + ks * 32 + q * 8;
      short8 bh = *(const short8*)(Bh + bo);
      short8 bl = *(const short8*)(Bl + bo);
      a2c = MFMA16(ah, bh, a2c);
      a2c = MFMA16(al, bh, a2c);
      a2c = MFMA16(ah, bl, a2c);
    }
    float* C = qkv + (size_t)sel * NE * D;
    #pragma unroll
    for (int r = 0; r < 4; ++r)
      C[(size_t)(row0 + 4 * q + r) * D + n0 + c] = a2c[r];
  }
}

// ---------- K4: sparse edge attention, one block (128 thr) per query edge --------
__global__ void attn_kernel(const float* __restrict__ q, const float* __restrict__ k,
                            const float* __restrict__ v, const int* __restrict__ src,
                            const int* __restrict__ dst, const int* __restrict__ deg,
                            const int* __restrict__ lists, float* __restrict__ ao) {
  int e = blockIdx.x;
  int j = threadIdx.x;  // head = j/32, d = j%32 (shfl_xor<32 stays in-head)
  float qj = q[e * D + j];
  int sn = src[e], dn = dst[e];
  float m = -1e30f, l = 0.f, acc = 0.f;
  const float scale = 0.17677669529663687f;  // 1/sqrt(32)
  int degA = max(0, min(deg[sn], CAP));
  for (int i = 0; i < degA; ++i) {
    int fe = lists[sn * CAP + i];
    float p = qj * k[fe * D + j];
    p += __shfl_xor(p, 16); p += __shfl_xor(p, 8); p += __shfl_xor(p, 4);
    p += __shfl_xor(p, 2);  p += __shfl_xor(p, 1);
    float s = p * scale;
    float vj = v[fe * D + j];
    float mn = fmaxf(m, s);
    float corr = expf(m - mn);
    float w = expf(s - mn);
    l = l * corr + w;
    acc = acc * corr + w * vj;
    m = mn;
  }
  if (dn != sn) {
    int degB = max(0, min(deg[dn], CAP));
    for (int i = 0; i < degB; ++i) {
      int fe = lists[dn * CAP + i];
      if (src[fe] == sn || dst[fe] == sn) continue;  // already in list A
      float p = qj * k[fe * D + j];
      p += __shfl_xor(p, 16); p += __shfl_xor(p, 8); p += __shfl_xor(p, 4);
      p += __shfl_xor(p, 2);  p += __shfl_xor(p, 1);
      float s = p * scale;
      float vj = v[fe * D + j];
      float mn = fmaxf(m, s);
      float corr = expf(m - mn);
      float w = expf(s - mn);
      l = l * corr + w;
      acc = acc * corr + w * vj;
      m = mn;
    }
  }
  ao[e * D + j] = acc / fmaxf(l, 1e-37f);
}

// ---------- K5: MFMA o = ao@WO; x = gelu(o@W1+b1); logits = x@W2+b2 (VALU) -------
__global__ __launch_bounds__(512) void o_mlp_mfma_kernel(
    const float* __restrict__ ao,
    const unsigned short* __restrict__ wtHi, const unsigned short* __restrict__ wtLo,
    const void* __restrict__ b1, const void* __restrict__ w2,
    const void* __restrict__ b2, const int* __restrict__ flag,
    void* __restrict__ out) {
  __shared__ __align__(16) float hf[8 * 64 * 4];  // frag-order o (8 KB)
  __shared__ float xl[16 * 132];                  // x row-major, padded
  __shared__ float w2l[128 * 16];
  int t = threadIdx.x;
  int wave = t >> 6, lane = t & 63;
  int q = lane >> 4, c = lane & 15;
  int f = flag[0];
  int row0 = blockIdx.x * 16;
  int n0 = wave * 16;
  const unsigned short* WOh = wtHi + 5 * 16384;
  const unsigned short* WOl = wtLo + 5 * 16384;
  const unsigned short* W1h = wtHi + 6 * 16384;
  const unsigned short* W1l = wtLo + 6 * 16384;

  // o = ao @ WO (A gathered straight from global fp32)
  floatx4 acc = {0.f, 0.f, 0.f, 0.f};
  #pragma unroll
  for (int ks = 0; ks < 4; ++ks) {
    int k0 = ks * 32 + q * 8;
    const float* ap = ao + (size_t)(row0 + c) * D + k0;
    float4 p0 = *(const float4*)ap;
    float4 p1 = *(const float4*)(ap + 4);
    float v8[8] = {p0.x, p0.y, p0.z, p0.w, p1.x, p1.y, p1.z, p1.w};
    short8 ah, al;
    build_frags(v8, ah, al);
    size_t bo = (size_t)(n0 + c) * 128 + k0;
    short8 bh = *(const short8*)(WOh + bo);
    short8 bl = *(const short8*)(WOl + bo);
    acc = MFMA16(ah, bh, acc);
    acc = MFMA16(al, bh, acc);
    acc = MFMA16(ah, bl, acc);
  }
  {
    int np = n0 + c;
    int kd = np >> 5, qd = (np >> 3) & 3, half = (c >> 2) & 1, j4 = c & 3;
    #pragma unroll
    for (int r = 0; r < 4; ++r)
      hf[((kd * 2 + half) * 64 + qd * 16 + 4 * q + r) * 4 + j4] = acc[r];
  }
  __syncthreads();
  // x = gelu(o @ W1 + b1)
  floatx4 a2c = {0.f, 0.f, 0.f, 0.f};
  #pragma unroll
  for (int ks = 0; ks < 4; ++ks) {
    float4 p0 = *(const float4*)&hf[((ks * 2 + 0) * 64 + lane) * 4];
    float4 p1 = *(const float4*)&hf[((ks * 2 + 1) * 64 + lane) * 4];
    float v8[8] = {p0.x, p0.y, p0.z, p0.w, p1.x, p1.y, p1.z, p1.w};
    short8 ah, al;
    build_frags(v8, ah, al);
    size_t bo = (size_t)(n0 + c) * 128 + ks * 32 + q * 8;
    short8 bh = *(const short8*)(W1h + bo);
    short8 bl = *(const short8*)(W1l + bo);
    a2c = MFMA16(ah, bh, a2c);
    a2c = MFMA16(al, bh, a2c);
    a2c = MFMA16(ah, bl, a2c);
  }
  float bj = ldx(b1, n0 + c, f);
  #pragma unroll
  for (int r = 0; r < 4; ++r) {
    float u = a2c[r] + bj;
    float inner = 0.7978845608028654f * (u + 0.044715f * u * u * u);
    xl[(4 * q + r) * 132 + n0 + c] = 0.5f * u * (1.f + tanhf(inner));
  }
  for (int i = t; i < D * 16; i += 512) w2l[i] = ldx(w2, i, f);
  __syncthreads();
  if (t < 256) {  // logits = x @ w2 + b2
    int r = t >> 4, cc = t & 15;
    float s = 0.f;
    for (int kk = 0; kk < D; ++kk) s += xl[r * 132 + kk] * w2l[kk * 16 + cc];
    s += ldx(b2, cc, f);
    int idx = (row0 + r) * 16 + cc;
    if (f) ((float*)out)[idx] = s;
    else ((__hip_bfloat16*)out)[idx] = __float2bfloat16(s);
  }
}

extern "C" void kernel_launch(void* const* d_in, const int* in_sizes, int n_in,
                              void* d_out, int out_size, void* d_ws, size_t ws_size,
                              hipStream_t stream) {
  const int* eidx = (const int*)d_in[2];
  const int* src = eidx;
  const int* dst = eidx + NE;

  size_t off = 0;
  char* base = (char*)d_ws;
  auto alloc = [&](size_t nbytes) -> void* {
    void* p = base + off;
    off += (nbytes + 255) & ~(size_t)255;
    return p;
  };
  int* flag              = (int*)alloc(256);
  float* ns              = (float*)alloc(NN * sizeof(float));
  float* es              = (float*)alloc(NE * sizeof(float));
  int* node_mask         = (int*)alloc(NN * sizeof(int));
  int* edge_topk         = (int*)alloc(NE * sizeof(int));
  int* deg               = (int*)alloc(NN * sizeof(int));
  int* lists             = (int*)alloc((size_t)NN * CAP * sizeof(int));
  unsigned short* wtHi   = (unsigned short*)alloc((size_t)7 * 16384 * sizeof(unsigned short));
  unsigned short* wtLo   = (unsigned short*)alloc((size_t)7 * 16384 * sizeof(unsigned short));
  float* qkv             = (float*)alloc((size_t)3 * NE * D * sizeof(float));
  float* ao              = (float*)alloc((size_t)NE * D * sizeof(float));
  float* qb = qkv, *kb = qkv + NE * D, *vb = qkv + 2 * NE * D;

  K1Args a1;
  a1.nf = d_in[0]; a1.ef = d_in[1]; a1.wrn = d_in[3]; a1.wre = d_in[4];
  a1.w[0] = d_in[5];  a1.w[1] = d_in[6];  a1.w[2] = d_in[7];
  a1.w[3] = d_in[8];  a1.w[4] = d_in[9];  a1.w[5] = d_in[10]; a1.w[6] = d_in[11];
  a1.ns = ns; a1.es = es; a1.deg = deg; a1.flag = flag;
  a1.wtHi = wtHi; a1.wtLo = wtLo;

  // K1: scores + flag + deg zero + weight split/transpose
  scores_prep_kernel<<<SCORE_BLOCKS + 1 + WPREP_BLOCKS, 256, 0, stream>>>(a1);
  // K2: top-k ranks + incident lists
  mask_lists_kernel<<<NMB + EMB + NE / 256, 256, 0, stream>>>(
      ns, es, src, dst, node_mask, edge_topk, deg, lists);
  // K3: MFMA h -> q,k,v
  h_qkv_mfma_kernel<<<NE / 16, 512, 0, stream>>>(
      d_in[1], d_in[0], src, dst, node_mask, edge_topk, flag, wtHi, wtLo, qkv);
  // K4: sparse attention
  attn_kernel<<<NE, 128, 0, stream>>>(qb, kb, vb, src, dst, deg, lists, ao);
  // K5: MFMA o -> gelu MLP -> logits
  o_mlp_mfma_kernel<<<NE / 16, 512, 0, stream>>>(
      ao, wtHi, wtLo, d_in[12], d_in[13], d_in[14], flag, d_out);
}